// Round 2
// baseline (172.467 us; speedup 1.0000x reference)
//
#include <hip/hip_runtime.h>

#define T_ 12
#define N_ 1370
#define MSEQ 64      // sequences per block = 4 waves x 16 seqs, waves independent
#define LDA 72       // h strip row stride in shorts (144B -> 2-way banks max, free)
#define NBLK 1370    // 87680 / 64
#define NFRAG 48     // 32 h-weight frags (reg-resident) + 16 x/bias frags (LDS)

typedef __attribute__((ext_vector_type(8))) short short8;
typedef __attribute__((ext_vector_type(4))) float floatx4;
typedef __attribute__((ext_vector_type(4))) unsigned uint4v;
typedef __attribute__((ext_vector_type(2))) unsigned uint2v;

#define NLOG2E -1.4426950408889634f
#define TLOG2E 2.8853900817779268f
#define N2LOG2E -5.7707801635558536f   // -2*TLOG2E

__device__ __forceinline__ short f2bf(float x) {
  unsigned u = __builtin_bit_cast(unsigned, x);
  u = (u + 0x7fffu + ((u >> 16) & 1u)) >> 16;
  return (short)u;
}
// HW packed f32->bf16 (RNE): low16 = bf16(a), high16 = bf16(b)
__device__ __forceinline__ unsigned pk_bf16(float a, float b) {
  unsigned r;
  asm("v_cvt_pk_bf16_f32 %0, %1, %2" : "=v"(r) : "v"(a), "v"(b));
  return r;
}
__device__ __forceinline__ short8 load_w8s(const float* __restrict__ p, float s) {
  floatx4 a = *(const floatx4*)p;
  floatx4 b = *(const floatx4*)(p + 4);
  uint4v u = {pk_bf16(a[0] * s, a[1] * s), pk_bf16(a[2] * s, a[3] * s),
              pk_bf16(b[0] * s, b[1] * s), pk_bf16(b[2] * s, b[3] * s)};
  return __builtin_bit_cast(short8, u);
}

// Barrier-free LSTM: each wave owns 16 seqs AND all 64 hidden units, so the
// h_t -> h_{t+1} dependency never crosses a wave. Per t, per wave: 16 MFMA
// m-tiles (4 gates x 4 unit-tiles (ut) x 3 k-chunks). h lives in a per-wave
// double-buffered LDS strip; write->read ordering is same-wave program order
// (compiler lgkmcnt), NO __syncthreads in the t loop.
// Swapped MFMA roles: A = weights (m = gate unit = ut*16+m16), B = [h|x|1]
// (n = seq = m16 within the wave's 16-seq strip). k: 0..63 = h, 64..71 = x
// (q==0), 72 = bias (q==1, j==0). D: col=lane&15 = seq, row=q*4+r = unit ->
// h writeback one ds_write_b64 at [m16][ut*16+q*4].
// 32 h-weight frags in VGPRs (128 regs); 16 x/bias frags (75% dead lanes)
// live in LDS, converted cooperatively (12 frags per wave) and re-read per t.
// Activation scales pre-folded: i,f,o rows by -log2e, g rows by 2*log2e;
// cell state carried pre-scaled by 2*log2e (see round-1 derivation).
__global__ void __launch_bounds__(256, 2) lstm_kernel(
    const float* __restrict__ x, const float* __restrict__ W_ih,
    const float* __restrict__ W_hh, const float* __restrict__ b_ih,
    const float* __restrict__ b_hh, const float* __restrict__ W_fc,
    const float* __restrict__ b_fc, float* __restrict__ out) {
  __shared__ short wlds[NFRAG][64][8];          // 48 KB: per-lane A-fragments
  __shared__ short hstrip[4][2][16][LDA];       // 18 KB: per-wave h, dbuf
  __shared__ __align__(16) short xbuf[T_][MSEQ][8];  // 12 KB
  __shared__ __align__(16) short ones_row[8];

  const int tid = threadIdx.x;
  const int wave = tid >> 6;
  const int lane = tid & 63;
  const int m16 = lane & 15;
  const int q = lane >> 4;
  const int blk = blockIdx.x;

  // ---- cooperative weight convert: wave w fills frag rows w*12..w*12+11 ----
  // fid 0..31: h-chunks, fid = ((g*4+ut)*2)|kc -> W_hh[grow][kc*32+q*8..+7]
  // fid 32..47: x/bias chunk, fid = 32 + g*4+ut
#pragma unroll
  for (int i = 0; i < 12; ++i) {
    const int fid = wave * 12 + i;
    short8 v = {0, 0, 0, 0, 0, 0, 0, 0};
    if (fid < 32) {
      const int gu = fid >> 1, kc = fid & 1;
      const int g = gu >> 2, ut = gu & 3;
      const float sg = (g == 2) ? TLOG2E : NLOG2E;
      const int grow = g * 64 + ut * 16 + m16;
      v = load_w8s(W_hh + grow * 64 + kc * 32 + q * 8, sg);
    } else {
      const int gu = fid - 32;
      const int g = gu >> 2, ut = gu & 3;
      const float sg = (g == 2) ? TLOG2E : NLOG2E;
      const int grow = g * 64 + ut * 16 + m16;
      if (q == 0) {
        v = load_w8s(W_ih + grow * 8, sg);        // k=64..71: x columns
      } else if (q == 1) {
        v[0] = f2bf(sg * (b_ih[grow] + b_hh[grow]));  // k=72: bias column
      }
    }
    *(short8*)&wlds[fid][lane][0] = v;
  }

  // ---- zero h strips (h0 = 0, pads = 0); ones row for the bias column ----
  {
    int* hp = (int*)hstrip;
#pragma unroll
    for (int i = tid; i < (int)(sizeof(hstrip) / 4); i += 256) hp[i] = 0;
    if (tid < 8) ones_row[tid] = (tid == 0) ? (short)0x3F80 : (short)0;
  }

  // ---- stage all 12 timesteps of x as bf16: float4 load + cvt_pk ----
  {
#pragma unroll
    for (int j = 0; j < 6; ++j) {
      const int slot = j * 256 + tid;   // 12t * 64seq * 2half = 1536 slots
      const int t = slot >> 7;
      const int idx = slot & 127;
      const int seq = idx >> 1;
      const int half = idx & 1;
      const int s0 = blk * MSEQ + seq;
      const int bidx = s0 / N_;
      const int nidx = s0 - bidx * N_;
      const floatx4 v = *(const floatx4*)(
          x + (((size_t)bidx * T_ + t) * N_ + nidx) * 8 + half * 4);
      uint2v u = {pk_bf16(v[0], v[1]), pk_bf16(v[2], v[3])};
      *(uint2v*)&xbuf[t][seq][half * 4] = u;
    }
  }
  __syncthreads();   // the ONLY barrier: weights staged, x staged, h zeroed

  // ---- pull the 32 h-weight frags into registers (conflict-free b128) ----
  short8 wA[4][4][2];
#pragma unroll
  for (int g = 0; g < 4; ++g)
#pragma unroll
    for (int ut = 0; ut < 4; ++ut)
#pragma unroll
      for (int kc = 0; kc < 2; ++kc)
        wA[g][ut][kc] =
            *(const short8*)&wlds[(((g << 2) | ut) << 1) | kc][lane][0];

  const floatx4 zacc = {0.0f, 0.0f, 0.0f, 0.0f};

  float cst[4][4];
#pragma unroll
  for (int ut = 0; ut < 4; ++ut)
#pragma unroll
    for (int r = 0; r < 4; ++r) cst[ut][r] = 0.0f;

#pragma unroll 2
  for (int t = 0; t < T_; ++t) {
    const int rb = t & 1, wb = rb ^ 1;
    short8 b0 = *(const short8*)&hstrip[wave][rb][m16][q * 8];
    short8 b1 = *(const short8*)&hstrip[wave][rb][m16][32 + q * 8];
    const short* bxp = q ? &ones_row[0] : &xbuf[t][wave * 16 + m16][0];
    short8 bx = *(const short8*)bxp;
#pragma unroll
    for (int ut = 0; ut < 4; ++ut) {
      short8 wx0 = *(const short8*)&wlds[32 + ut][lane][0];
      short8 wx1 = *(const short8*)&wlds[36 + ut][lane][0];
      short8 wx2 = *(const short8*)&wlds[40 + ut][lane][0];
      short8 wx3 = *(const short8*)&wlds[44 + ut][lane][0];
      floatx4 gi = __builtin_amdgcn_mfma_f32_16x16x32_bf16(wA[0][ut][0], b0, zacc, 0, 0, 0);
      floatx4 gf = __builtin_amdgcn_mfma_f32_16x16x32_bf16(wA[1][ut][0], b0, zacc, 0, 0, 0);
      floatx4 gg = __builtin_amdgcn_mfma_f32_16x16x32_bf16(wA[2][ut][0], b0, zacc, 0, 0, 0);
      floatx4 go = __builtin_amdgcn_mfma_f32_16x16x32_bf16(wA[3][ut][0], b0, zacc, 0, 0, 0);
      gi = __builtin_amdgcn_mfma_f32_16x16x32_bf16(wA[0][ut][1], b1, gi, 0, 0, 0);
      gf = __builtin_amdgcn_mfma_f32_16x16x32_bf16(wA[1][ut][1], b1, gf, 0, 0, 0);
      gg = __builtin_amdgcn_mfma_f32_16x16x32_bf16(wA[2][ut][1], b1, gg, 0, 0, 0);
      go = __builtin_amdgcn_mfma_f32_16x16x32_bf16(wA[3][ut][1], b1, go, 0, 0, 0);
      gi = __builtin_amdgcn_mfma_f32_16x16x32_bf16(wx0, bx, gi, 0, 0, 0);
      gf = __builtin_amdgcn_mfma_f32_16x16x32_bf16(wx1, bx, gf, 0, 0, 0);
      gg = __builtin_amdgcn_mfma_f32_16x16x32_bf16(wx2, bx, gg, 0, 0, 0);
      go = __builtin_amdgcn_mfma_f32_16x16x32_bf16(wx3, bx, go, 0, 0, 0);
      float hv[4];
#pragma unroll
      for (int r = 0; r < 4; ++r) {
        float di = 1.0f + __builtin_amdgcn_exp2f(gi[r]);
        float df = 1.0f + __builtin_amdgcn_exp2f(gf[r]);
        float dg = 1.0f + __builtin_amdgcn_exp2f(gg[r]);
        float dq = 1.0f + __builtin_amdgcn_exp2f(go[r]);
        float pa = di * df, pb = dg * dq;
        float rp = __builtin_amdgcn_rcpf(pa * pb);
        float fv = rp * di * pb;                       // 1/df = f
        float rpa = rp * pa;
        float ov = rpa * dg;                           // 1/dq = o
        float tg = fmaf(TLOG2E, dg, N2LOG2E);          // (dg-2)*2log2e
        float ig = tg * rp * (df * dq);                // i*g*2log2e
        float cs = fmaf(fv, cst[ut][r], ig);           // c*2log2e
        cst[ut][r] = cs;
        float dt = 1.0f + __builtin_amdgcn_exp2f(cs);
        float tc = fmaf(-2.0f, __builtin_amdgcn_rcpf(dt), 1.0f);  // tanh(c)
        hv[r] = ov * tc;
      }
      // one b64 write: h for seq m16, units ut*16+q*4 .. +3 (next buffer)
      unsigned long long pk =
          (unsigned long long)pk_bf16(hv[0], hv[1]) |
          ((unsigned long long)pk_bf16(hv[2], hv[3]) << 32);
      *(unsigned long long*)&hstrip[wave][wb][m16][ut * 16 + q * 4] = pk;
    }
  }

  // ---- final FC: y = h_T @ W_fc^T + b_fc; h_T is in hstrip[wave][0] ----
  {
    short8 f0, f1;
    short8 z = {0, 0, 0, 0, 0, 0, 0, 0};
    if (m16 < 8) {
      const float* wr = W_fc + m16 * 64;
      f0 = load_w8s(wr + q * 8, 1.0f);
      f1 = load_w8s(wr + 32 + q * 8, 1.0f);
    } else {
      f0 = z;
      f1 = z;
    }
    short8 h0 = *(const short8*)&hstrip[wave][0][m16][q * 8];
    short8 h1 = *(const short8*)&hstrip[wave][0][m16][32 + q * 8];
    floatx4 acc = __builtin_amdgcn_mfma_f32_16x16x32_bf16(f0, h0, zacc, 0, 0, 0);
    acc = __builtin_amdgcn_mfma_f32_16x16x32_bf16(f1, h1, acc, 0, 0, 0);
    if (q < 2) {
      const int orow = blk * MSEQ + wave * 16 + m16;
#pragma unroll
      for (int r = 0; r < 4; ++r)
        out[orow * 8 + q * 4 + r] = acc[r] + b_fc[q * 4 + r];
    }
  }
}

extern "C" void kernel_launch(void* const* d_in, const int* in_sizes, int n_in,
                              void* d_out, int out_size, void* d_ws,
                              size_t ws_size, hipStream_t stream) {
  const float* x    = (const float*)d_in[0];
  const float* W_ih = (const float*)d_in[1];
  const float* W_hh = (const float*)d_in[2];
  const float* b_ih = (const float*)d_in[3];
  const float* b_hh = (const float*)d_in[4];
  const float* W_fc = (const float*)d_in[5];
  const float* b_fc = (const float*)d_in[6];
  float* out = (float*)d_out;
  hipLaunchKernelGGL(lstm_kernel, dim3(NBLK), dim3(256), 0, stream,
                     x, W_ih, W_hh, b_ih, b_hh, W_fc, b_fc, out);
}